// Round 5
// baseline (896.136 us; speedup 1.0000x reference)
//
#include <hip/hip_runtime.h>
#include <stdint.h>

#define BATCH 2048
#define IN_DIM 1024
#define HID 32768
#define TOPK 32

#define GCAP 4096          // global candidate cap per row
#define LCAP 32            // per-block per-row cap
#define OVFBIT 0x40000000
#define DELTA 0.09375f
#define MAXC 512

typedef __attribute__((ext_vector_type(8))) short short8;
typedef __attribute__((ext_vector_type(4))) float f32x4;

__device__ __forceinline__ ushort f2bf(float f) {
    uint32_t u = __float_as_uint(f);
    return (ushort)((u + 0x7FFFu + ((u >> 16) & 1u)) >> 16);
}
__device__ __forceinline__ float bf2f(ushort u) {
    return __uint_as_float(((uint32_t)u) << 16);
}

// =====================================================================
// FAST PATH
// =====================================================================

// ---------- fused: x->bf16, We->bf16, zero gcnt ----------
#define XB (BATCH * IN_DIM / 4 / 256)            // 2048 blocks
#define WB (HID * IN_DIM / 4 / 256)              // 32768 blocks

__global__ __launch_bounds__(256) void convert_zero(
    const float* __restrict__ x, const float* __restrict__ We,
    ushort* __restrict__ xbf, ushort* __restrict__ wbf,
    int* __restrict__ gcnt)
{
    const int b = blockIdx.x, t = threadIdx.x;
    if (b < XB) {
        const int i = b * 256 + t;
        float4 v = ((const float4*)x)[i];
        ushort4 o; o.x = f2bf(v.x); o.y = f2bf(v.y); o.z = f2bf(v.z); o.w = f2bf(v.w);
        ((ushort4*)xbf)[i] = o;
    } else if (b < XB + WB) {
        const int i = (b - XB) * 256 + t;
        float4 v = ((const float4*)We)[i];
        ushort4 o; o.x = f2bf(v.x); o.y = f2bf(v.y); o.z = f2bf(v.z); o.w = f2bf(v.w);
        ((ushort4*)wbf)[i] = o;
    } else {
        const int i = (b - XB - WB) * 256 + t;
        if (i < BATCH) gcnt[i] = 0;
    }
}

// ---------- bf16 MFMA encode + h-zero + candidate compaction ----------
__global__ __launch_bounds__(256) void encode_mfma(
    const ushort* __restrict__ xb, const ushort* __restrict__ wb,
    const float* __restrict__ be, float* __restrict__ h,
    int* __restrict__ gcnt, uint32_t* __restrict__ glist)
{
    __shared__ __align__(16) ushort ABs[2 * 128 * 32];  // As | Bs; reused as lists
    __shared__ int rowcnt[128];
    ushort* As = ABs;
    ushort* Bs = ABs + 128 * 32;

    const int t    = threadIdx.x;
    const int wave = t >> 6;
    const int lane = t & 63;
    const int m0 = blockIdx.y * 128;
    const int n0 = blockIdx.x * 128;
    const int wm = (wave >> 1) * 64;
    const int wn = (wave & 1) * 64;

    if (t < 128) rowcnt[t] = 0;   // ordered before use by K-loop barriers

    const int srow = lane >> 2;
    const int scol = (lane & 3) * 8;
    const ushort* gA0 = xb + (size_t)(m0 + wave * 32 + srow) * IN_DIM + scol;
    const ushort* gA1 = gA0 + 16 * IN_DIM;
    const ushort* gB0 = wb + (size_t)(n0 + wave * 32 + srow) * IN_DIM + scol;
    const ushort* gB1 = gB0 + 16 * IN_DIM;
    ushort* lA0 = &As[(wave * 32 + 0)  * 32];
    ushort* lA1 = &As[(wave * 32 + 16) * 32];
    ushort* lB0 = &Bs[(wave * 32 + 0)  * 32];
    ushort* lB1 = &Bs[(wave * 32 + 16) * 32];

    f32x4 acc[4][4];
    #pragma unroll
    for (int i = 0; i < 4; i++)
        #pragma unroll
        for (int j = 0; j < 4; j++) acc[i][j] = 0.f;

    const int fr   = lane & 15;
    const int quad = lane >> 4;

    for (int kt = 0; kt < IN_DIM; kt += 32) {
        __builtin_amdgcn_global_load_lds((const __attribute__((address_space(1))) void*)(gA0 + kt),
                                         (__attribute__((address_space(3))) void*)lA0, 16, 0, 0);
        __builtin_amdgcn_global_load_lds((const __attribute__((address_space(1))) void*)(gA1 + kt),
                                         (__attribute__((address_space(3))) void*)lA1, 16, 0, 0);
        __builtin_amdgcn_global_load_lds((const __attribute__((address_space(1))) void*)(gB0 + kt),
                                         (__attribute__((address_space(3))) void*)lB0, 16, 0, 0);
        __builtin_amdgcn_global_load_lds((const __attribute__((address_space(1))) void*)(gB1 + kt),
                                         (__attribute__((address_space(3))) void*)lB1, 16, 0, 0);
        __syncthreads();
        short8 af[4], bf[4];
        #pragma unroll
        for (int i = 0; i < 4; i++) {
            af[i] = *(const short8*)&As[(wm + i * 16 + fr) * 32 + quad * 8];
            bf[i] = *(const short8*)&Bs[(wn + i * 16 + fr) * 32 + quad * 8];
        }
        #pragma unroll
        for (int mt = 0; mt < 4; mt++)
            #pragma unroll
            for (int nt = 0; nt < 4; nt++)
                acc[mt][nt] = __builtin_amdgcn_mfma_f32_16x16x32_bf16(
                    af[mt], bf[nt], acc[mt][nt], 0, 0, 0);
        __syncthreads();
    }
    // After the final barrier: As/Bs dead -> reuse as candidate lists.
    uint32_t* lists = (uint32_t*)ABs;   // 128 rows x LCAP entries

    // --- zero the h tile (final h = zeros + topk winner scatter) ---
    {
        float4 z; z.x = z.y = z.z = z.w = 0.f;
        #pragma unroll
        for (int j = 0; j < 16; j++) {
            const int idx = t + j * 256;       // 4096 float4 slots = 128x128
            const int r = idx >> 5, c = idx & 31;
            ((float4*)(h + (size_t)(m0 + r) * HID + n0))[c] = z;
        }
    }

    // --- candidate compaction straight from accumulators ---
    // C/D layout: col(n)=lane&15, row(m)=quad*4+reg  [m89/m91-verified]
    #pragma unroll
    for (int nt = 0; nt < 4; nt++) {
        const int nl = wn + nt * 16 + fr;
        const float bias = be[n0 + nl];
        #pragma unroll
        for (int mt = 0; mt < 4; mt++) {
            #pragma unroll
            for (int r = 0; r < 4; r++) {
                float v = acc[mt][nt][r] + bias;
                if (v >= 0.5f) {
                    const int ml = wm + mt * 16 + quad * 4 + r;     // local row
                    const uint32_t n = (uint32_t)(n0 + nl);          // global col
                    int pos = atomicAdd(&rowcnt[ml], 1);
                    if (pos < LCAP)
                        lists[ml * LCAP + pos] = (n << 16) | (uint32_t)f2bf(v);
                }
            }
        }
    }
    __syncthreads();

    // --- publish per-row lists to global ---
    if (t < 128) {
        const int c   = rowcnt[t];
        const int row = m0 + t;
        if (c > LCAP) {
            atomicOr(&gcnt[row], OVFBIT);
        } else if (c > 0) {
            int gb = atomicAdd(&gcnt[row], c);
            if (gb + c > GCAP) {
                atomicOr(&gcnt[row], OVFBIT);
            } else {
                for (int i = 0; i < c; i++)
                    glist[(size_t)row * GCAP + gb + i] = lists[t * LCAP + i];
            }
        }
    }
}

// ---------- fused: per-row topk+rerank (blocks < BATCH) | Wd transpose->bf16 ----------
__global__ __launch_bounds__(1024) void topk_transpose(
    const int* __restrict__ gcnt, const uint32_t* __restrict__ glist,
    const ushort* __restrict__ xbf, const ushort* __restrict__ wbf,
    const float* __restrict__ x, const float* __restrict__ We,
    const float* __restrict__ be, float* __restrict__ h,
    int* __restrict__ wIdx, float* __restrict__ wVal,
    const float* __restrict__ Wd, ushort* __restrict__ WdT)
{
    __shared__ __align__(16) uint32_t sm[9216];   // 36 KB, branch-dependent layout
    const int tid = threadIdx.x;

    if (blockIdx.x >= BATCH) {
        // ===== transpose part: Wd [1024][32768] fp32 -> WdT [32768][1024] bf16
        const int g = tid >> 8, u = tid & 255;
        ushort* tl = (ushort*)sm + g * (64 * 69);                 // 4 x 8832 B
        const int tile = (blockIdx.x - BATCH) * 4 + g;            // 0..8191
        const int j0 = (tile & 511) * 64;                         // HID
        const int i0 = (tile >> 9) * 64;                          // IN_DIM
        const int c4 = (u & 15) * 4;
        const int r0 = u >> 4;
        #pragma unroll
        for (int s = 0; s < 4; s++) {
            const int r = r0 + s * 16;
            float4 v = *(const float4*)&Wd[(size_t)(i0 + r) * HID + j0 + c4];
            tl[r * 69 + c4 + 0] = f2bf(v.x); tl[r * 69 + c4 + 1] = f2bf(v.y);
            tl[r * 69 + c4 + 2] = f2bf(v.z); tl[r * 69 + c4 + 3] = f2bf(v.w);
        }
        __syncthreads();
        #pragma unroll
        for (int s = 0; s < 4; s++) {
            const int jr = r0 + s * 16;
            ushort4 o;
            o.x = tl[(c4 + 0) * 69 + jr]; o.y = tl[(c4 + 1) * 69 + jr];
            o.z = tl[(c4 + 2) * 69 + jr]; o.w = tl[(c4 + 3) * 69 + jr];
            *(ushort4*)&WdT[(size_t)(j0 + jr) * IN_DIM + i0 + c4] = o;
        }
        return;
    }

    // ===== topk part =====
    const int row = blockIdx.x;
    uint32_t* ent   = sm;                         // up to 4096 entries
    int*      hist  = (int*)(sm + 4096);          // 256
    float*    xs    = (float*)(sm + 4352);        // 1024
    int*      c_idx = (int*)(sm + 5376);          // 512
    float*    c_val = (float*)(sm + 5888);        // 512
    int*      win_i = (int*)(sm + 6400);          // 32
    float*    win_v = (float*)(sm + 6432);        // 32
    int*      s_wave= (int*)(sm + 6464);          // 16
    int*      s_sc  = (int*)(sm + 6480);          // scalars: [0]=c_n [1]=b [2]=ncand [3]=c05
    ushort*   xsb   = (ushort*)(sm + 6656);       // 1024 bf16 (fallback)

    xs[tid] = x[(size_t)row * IN_DIM + tid];
    if (tid < 256) hist[tid] = 0;
    if (tid == 0) { s_sc[0] = 0; }

    const int cnt = gcnt[row];
    bool listok = !(cnt & OVFBIT) && cnt >= TOPK && cnt <= GCAP;
    float th = 0.f;
    bool fell_back = false;

    if (listok) {
        __syncthreads();
        for (int i = tid; i < cnt; i += 1024) {
            uint32_t e = glist[(size_t)row * GCAP + i];
            ent[i] = e;
            int bb = (int)((bf2f((ushort)(e & 0xFFFFu)) - 0.5f) * 128.f);
            if (bb > 255) bb = 255;
            atomicAdd(&hist[bb], 1);
        }
        __syncthreads();
        if (tid == 0) {
            int acc2 = 0, b = 255;
            for (; b >= 0; b--) { acc2 += hist[b]; if (acc2 >= TOPK) break; }
            int ncand = acc2;
            int lo = b - 12; if (lo < 0) lo = 0;
            for (int bb = b - 1; bb >= lo; bb--) ncand += hist[bb];
            s_sc[1] = b; s_sc[2] = ncand;
        }
        __syncthreads();
        const int b = s_sc[1];
        // b>=12 guarantees threshold >= 0.5 (prefilter-complete); ncand cap.
        if (b >= 12 && s_sc[2] <= MAXC) {
            th = 0.5f + (float)b * (1.f / 128.f) - DELTA;
            for (int i = tid; i < cnt; i += 1024) {
                uint32_t e = ent[i];
                if (bf2f((ushort)(e & 0xFFFFu)) >= th) {
                    int p = atomicAdd(&s_sc[0], 1);
                    if (p < MAXC) c_idx[p] = (int)(e >> 16);
                }
            }
        } else {
            listok = false;
        }
    }

    if (!listok) {
        // ======== guaranteed-correct fallback: recompute approx scores ========
        fell_back = true;
        xsb[tid] = xbf[(size_t)row * IN_DIM + tid];
        if (tid < 256) hist[tid] = 0;
        if (tid == 0) s_sc[0] = 0;
        __syncthreads();
        float a[32];
        for (int i = 0; i < 32; i++) {
            const int n = tid * 32 + i;
            const ushort* wr = wbf + (size_t)n * IN_DIM;
            float s = 0.f;
            for (int k = 0; k < IN_DIM; k++) s += bf2f(xsb[k]) * bf2f(wr[k]);
            s += be[n];
            a[i] = s > 0.f ? s : 0.f;
        }
        // count >= 0.5
        int loc = 0;
        for (int i = 0; i < 32; i++) loc += (a[i] >= 0.5f) ? 1 : 0;
        for (int off = 32; off > 0; off >>= 1) loc += __shfl_down(loc, off);
        if ((tid & 63) == 0) s_wave[tid >> 6] = loc;
        __syncthreads();
        if (tid == 0) {
            int tot = 0;
            for (int w = 0; w < 16; w++) tot += s_wave[w];
            s_sc[3] = tot;
        }
        __syncthreads();
        const bool  hi   = (s_sc[3] >= TOPK);
        const float base = hi ? 0.5f : 0.0f;
        for (int i = 0; i < 32; i++) {
            const bool in = hi ? (a[i] >= 0.5f) : (a[i] > 0.f);
            if (in) {
                int bb = (int)((a[i] - base) * 128.f);
                if (bb > 255) bb = 255;
                atomicAdd(&hist[bb], 1);
            }
        }
        __syncthreads();
        if (tid == 0) {
            int acc2 = 0, b = 255;
            for (; b >= 0; b--) { acc2 += hist[b]; if (acc2 >= TOPK) break; }
            s_sc[1] = b;
        }
        __syncthreads();
        th = (s_sc[1] >= 0) ? (base + (float)s_sc[1] * (1.f / 128.f) - DELTA) : 0.f;
        for (int i = 0; i < 32; i++) {
            if (a[i] > 0.f && a[i] >= th) {
                int p = atomicAdd(&s_sc[0], 1);
                if (p < MAXC) c_idx[p] = tid * 32 + i;
            }
        }
    }
    __syncthreads();
    const int nc = s_sc[0] < MAXC ? s_sc[0] : MAXC;
    (void)fell_back;

    // ===== exact fp32 recompute, one wave per candidate =====
    const int wv = tid >> 6, ln = tid & 63;
    for (int c = wv; c < nc; c += 16) {
        const float4* wr = (const float4*)(We + (size_t)c_idx[c] * IN_DIM);
        const float4* xv = (const float4*)xs;
        float s = 0.f;
        #pragma unroll
        for (int q = 0; q < 4; q++) {
            float4 w4 = wr[ln * 4 + q];
            float4 x4 = xv[ln * 4 + q];
            s += w4.x * x4.x + w4.y * x4.y + w4.z * x4.z + w4.w * x4.w;
        }
        #pragma unroll
        for (int off = 32; off > 0; off >>= 1) s += __shfl_down(s, off);
        if (ln == 0) {
            s += be[c_idx[c]];
            c_val[c] = s > 0.f ? s : 0.f;
        }
    }
    if (tid < TOPK) {   // prefill (covers nc < 32)
        win_i[tid] = -1; win_v[tid] = 0.f;
        wIdx[tid * BATCH + row] = 0;
        wVal[tid * BATCH + row] = 0.f;
    }
    __syncthreads();

    // exact ranking, ties -> lowest index (jax.lax.top_k semantics)
    if (tid < nc) {
        const float v = c_val[tid];
        const int  id = c_idx[tid];
        int r = 0;
        for (int j = 0; j < nc; j++) {
            float vj = c_val[j]; int ij = c_idx[j];
            r += (vj > v) || (vj == v && ij < id) ? 1 : 0;
        }
        if (r < TOPK) {
            win_i[r] = id; win_v[r] = v;
            wIdx[r * BATCH + row] = id;
            wVal[r * BATCH + row] = v;
        }
    }
    __syncthreads();

    // h is pre-zeroed by encode; scatter the exact winners only
    if (tid < TOPK && win_i[tid] >= 0)
        h[(size_t)row * HID + win_i[tid]] = win_v[tid];
}

// ---------- batch-major sparse decode from bf16 WdT ----------
__global__ __launch_bounds__(256) void decode_gather(
    const ushort* __restrict__ WdT, const float* __restrict__ bd,
    const int* __restrict__ wIdx, const float* __restrict__ wVal,
    float* __restrict__ xhat)
{
    const int b = blockIdx.x;
    const int t = threadIdx.x;
    __shared__ int   s_idx[TOPK];
    __shared__ float s_val[TOPK];
    if (t < TOPK) {
        s_idx[t] = wIdx[t * BATCH + b];
        s_val[t] = wVal[t * BATCH + b];
    }
    float4 acc = ((const float4*)bd)[t];
    __syncthreads();
    #pragma unroll 8
    for (int k = 0; k < TOPK; k++) {
        const ushort4 w = ((const ushort4*)(WdT + (size_t)s_idx[k] * IN_DIM))[t];
        const float  v = s_val[k];
        acc.x += v * bf2f(w.x); acc.y += v * bf2f(w.y);
        acc.z += v * bf2f(w.z); acc.w += v * bf2f(w.w);
    }
    ((float4*)(xhat + (size_t)b * IN_DIM))[t] = acc;
}

// =====================================================================
// FALLBACK PATH (fp32, round-1; used only if ws_size < 165 MiB)
// =====================================================================
#define BM 64
#define BN 128
#define BK 16
#define LDA 68
#define LDB 132

__global__ __launch_bounds__(256) void encode_gemm(
    const float* __restrict__ x, const float* __restrict__ We,
    const float* __restrict__ be, float* __restrict__ h)
{
    __shared__ __align__(16) float As2[BK][LDA];
    __shared__ __align__(16) float Bs2[BK][LDB];
    const int n0 = blockIdx.x * BN;
    const int m0 = blockIdx.y * BM;
    const int t  = threadIdx.x;
    const int tx = t & 15;
    const int ty = t >> 4;
    const int ar = t >> 2;
    const int ak = (t & 3) * 4;

    const float* ap  = x  + (size_t)(m0 + ar) * IN_DIM + ak;
    const float* bp0 = We + (size_t)(n0 + ar) * IN_DIM + ak;
    const float* bp1 = We + (size_t)(n0 + 64 + ar) * IN_DIM + ak;

    float acc[4][8] = {};
    for (int kt = 0; kt < IN_DIM; kt += BK) {
        float4 av  = *(const float4*)(ap  + kt);
        float4 bv0 = *(const float4*)(bp0 + kt);
        float4 bv1 = *(const float4*)(bp1 + kt);
        __syncthreads();
        As2[ak+0][ar] = av.x;  As2[ak+1][ar] = av.y;  As2[ak+2][ar] = av.z;  As2[ak+3][ar] = av.w;
        Bs2[ak+0][ar] = bv0.x; Bs2[ak+1][ar] = bv0.y; Bs2[ak+2][ar] = bv0.z; Bs2[ak+3][ar] = bv0.w;
        Bs2[ak+0][ar+64] = bv1.x; Bs2[ak+1][ar+64] = bv1.y; Bs2[ak+2][ar+64] = bv1.z; Bs2[ak+3][ar+64] = bv1.w;
        __syncthreads();
        #pragma unroll
        for (int kk = 0; kk < BK; kk++) {
            float a_[4], b_[8];
            *(float4*)a_     = *(const float4*)&As2[kk][ty*4];
            *(float4*)b_     = *(const float4*)&Bs2[kk][tx*8];
            *(float4*)(b_+4) = *(const float4*)&Bs2[kk][tx*8+4];
            #pragma unroll
            for (int i = 0; i < 4; i++)
                #pragma unroll
                for (int j = 0; j < 8; j++)
                    acc[i][j] += a_[i] * b_[j];
        }
    }
    float be_[8];
    *(float4*)be_     = *(const float4*)&be[n0 + tx*8];
    *(float4*)(be_+4) = *(const float4*)&be[n0 + tx*8 + 4];
    #pragma unroll
    for (int i = 0; i < 4; i++) {
        float o[8];
        #pragma unroll
        for (int j = 0; j < 8; j++) {
            float v = acc[i][j] + be_[j];
            o[j] = v > 0.0f ? v : 0.0f;
        }
        float* dst = h + (size_t)(m0 + ty*4 + i) * HID + n0 + tx*8;
        *(float4*)dst     = *(const float4*)o;
        *(float4*)(dst+4) = *(const float4*)(o+4);
    }
}

__global__ __launch_bounds__(1024) void topk_mask(
    float* __restrict__ h, int* __restrict__ wIdx, float* __restrict__ wVal)
{
    const int row = blockIdx.x;
    const int tid = threadIdx.x;
    float* hrow = h + (size_t)row * HID;

    uint32_t u[32];
    #pragma unroll
    for (int i = 0; i < 32; i++)
        u[i] = __float_as_uint(hrow[tid + (i << 10)]);

    __shared__ int s_wave[16];
    __shared__ int s_total;
    __shared__ int s_cgt;
    __shared__ int s_ceq;
    __shared__ int s_keep;
    __shared__ int s_eq[64];

    uint32_t lo = 0;
    for (int bit = 30; bit >= 0; bit--) {
        uint32_t cand = lo | (1u << bit);
        int local = 0;
        #pragma unroll
        for (int i = 0; i < 32; i++) local += (u[i] >= cand) ? 1 : 0;
        #pragma unroll
        for (int off = 32; off > 0; off >>= 1) local += __shfl_down(local, off);
        if ((tid & 63) == 0) s_wave[tid >> 6] = local;
        __syncthreads();
        if (tid == 0) {
            int tot = 0;
            #pragma unroll
            for (int w = 0; w < 16; w++) tot += s_wave[w];
            s_total = tot;
        }
        __syncthreads();
        if (s_total >= TOPK) lo = cand;
        __syncthreads();
    }
    const uint32_t T = lo;

    if (tid == 0) { s_cgt = 0; s_ceq = 0; }
    __syncthreads();

    #pragma unroll
    for (int i = 0; i < 32; i++) {
        int idx = tid + (i << 10);
        if (u[i] > T) {
            int p = atomicAdd(&s_cgt, 1);
            wIdx[p * BATCH + row] = idx;
            wVal[p * BATCH + row] = __uint_as_float(u[i]);
        } else if (T != 0u && u[i] == T) {
            int p = atomicAdd(&s_ceq, 1);
            if (p < 64) s_eq[p] = idx;
        }
    }
    __syncthreads();

    if (tid == 0) {
        int c = s_cgt;
        int r = TOPK - c;
        if (T == 0u) {
            for (int q = 0; q < r; q++) {
                wIdx[(c + q) * BATCH + row] = 0;
                wVal[(c + q) * BATCH + row] = 0.0f;
            }
            s_keep = 0;
        } else {
            int e = s_ceq; if (e > 64) e = 64;
            for (int a2 = 1; a2 < e; a2++) {
                int key = s_eq[a2]; int b2 = a2 - 1;
                while (b2 >= 0 && s_eq[b2] > key) { s_eq[b2+1] = s_eq[b2]; b2--; }
                s_eq[b2+1] = key;
            }
            if (r > e) r = e;
            for (int q = 0; q < r; q++) {
                wIdx[(c + q) * BATCH + row] = s_eq[q];
                wVal[(c + q) * BATCH + row] = __uint_as_float(T);
            }
            for (int q = c + r; q < TOPK; q++) {
                wIdx[q * BATCH + row] = 0; wVal[q * BATCH + row] = 0.0f;
            }
            s_keep = r;
        }
    }
    __syncthreads();
    const int r2 = s_keep;

    #pragma unroll
    for (int i = 0; i < 32; i++) {
        int idx = tid + (i << 10);
        uint32_t uu = u[i];
        bool keep = uu > T;
        if (!keep && T != 0u && uu == T) {
            for (int q = 0; q < r2; q++) keep = keep || (s_eq[q] == idx);
        }
        hrow[idx] = keep ? __uint_as_float(uu) : 0.0f;
    }
}

#define DCHUNK 16384

__global__ __launch_bounds__(256) void decode_sparse(
    const float* __restrict__ Wd, const float* __restrict__ bd,
    const int* __restrict__ wIdx, const float* __restrict__ wVal,
    float* __restrict__ xhat)
{
    extern __shared__ float lds[];
    const int i = blockIdx.x;
    const int t = threadIdx.x;
    const float* wrow = Wd + (size_t)i * HID;
    const float bias = bd[i];
    float acc[8];
    #pragma unroll
    for (int q = 0; q < 8; q++) acc[q] = bias;

    for (int ch = 0; ch < HID / DCHUNK; ch++) {
        __syncthreads();
        const float4* src = (const float4*)(wrow + ch * DCHUNK);
        #pragma unroll
        for (int j = 0; j < DCHUNK / 4 / 256; j++)
            ((float4*)lds)[t + j * 256] = src[t + j * 256];
        __syncthreads();
        const uint32_t base = (uint32_t)(ch * DCHUNK);
        #pragma unroll
        for (int q = 0; q < 8; q++) {
            const int b = t + (q << 8);
            #pragma unroll 4
            for (int k = 0; k < TOPK; k++) {
                uint32_t off = (uint32_t)wIdx[(k << 11) + b] - base;
                if (off < (uint32_t)DCHUNK)
                    acc[q] += wVal[(k << 11) + b] * lds[off];
            }
        }
    }
    #pragma unroll
    for (int q = 0; q < 8; q++) {
        const int b = t + (q << 8);
        xhat[(size_t)b * IN_DIM + i] = acc[q];
    }
}

// =====================================================================
extern "C" void kernel_launch(void* const* d_in, const int* in_sizes, int n_in,
                              void* d_out, int out_size, void* d_ws, size_t ws_size,
                              hipStream_t stream)
{
    const float* x  = (const float*)d_in[0];
    const float* We = (const float*)d_in[1];
    const float* be = (const float*)d_in[2];
    const float* Wd = (const float*)d_in[3];
    const float* bd = (const float*)d_in[4];

    float* xhat = (float*)d_out;                               // [2048,1024]
    float* h    = (float*)d_out + (size_t)BATCH * IN_DIM;      // [2048,32768]

    const size_t MiB = 1ull << 20;
    // ws layout: xbf @0 (4), wbf @4 (64), wIdx @68 (0.25), wVal @68.25 (0.25),
    // gcnt @68.5 (8 KiB), glist @69 (32), WdT bf16 @101 (64) -> need 165 MiB
    const size_t need = 165 * MiB;

    if (ws_size >= need) {
        ushort*   xbf  = (ushort*)d_ws;
        ushort*   wbf  = (ushort*)((char*)d_ws + 4 * MiB);
        int*      wIdx = (int*)   ((char*)d_ws + 68 * MiB);
        float*    wVal = (float*) ((char*)d_ws + 68 * MiB + 256 * 1024);
        int*      gcnt = (int*)   ((char*)d_ws + 68 * MiB + 512 * 1024);
        uint32_t* glist= (uint32_t*)((char*)d_ws + 69 * MiB);
        ushort*   WdT  = (ushort*)((char*)d_ws + 101 * MiB);

        convert_zero<<<XB + WB + 8, 256, 0, stream>>>(x, We, xbf, wbf, gcnt);
        encode_mfma<<<dim3(HID / 128, BATCH / 128), 256, 0, stream>>>(xbf, wbf, be, h, gcnt, glist);
        topk_transpose<<<BATCH + 2048, 1024, 0, stream>>>(gcnt, glist, xbf, wbf, x, We, be, h,
                                                          wIdx, wVal, Wd, WdT);
        decode_gather<<<BATCH, 256, 0, stream>>>(WdT, bd, wIdx, wVal, xhat);
    } else {
        int*   wIdx = (int*)d_ws;
        float* wVal = (float*)((char*)d_ws + sizeof(int) * BATCH * TOPK);
        dim3 g1(HID / BN, BATCH / BM);
        encode_gemm<<<g1, 256, 0, stream>>>(x, We, be, h);
        topk_mask<<<BATCH, 1024, 0, stream>>>(h, wIdx, wVal);
        decode_sparse<<<IN_DIM, 256, 65536, stream>>>(Wd, bd, wIdx, wVal, xhat);
    }
}